// Round 3
// baseline (475.000 us; speedup 1.0000x reference)
//
#include <hip/hip_runtime.h>

#define K_DIM 8192
#define N_DIM 8192
#define M_DIM 64
#define KSPLIT 16
#define KBLK (K_DIM / KSPLIT)   // 512 k per block

typedef __attribute__((ext_vector_type(8))) short bf16x8;   // 8 bf16 in 4 VGPRs
typedef __attribute__((ext_vector_type(4))) float fx4;

__device__ __forceinline__ short bf16_rne(float f) {
    unsigned u = __builtin_bit_cast(unsigned, f);
    u += 0x7FFFu + ((u >> 16) & 1u);
    return (short)(u >> 16);
}

// ---- x fp32 -> bf16 pre-convert (64*8192 elems, 8 per thread) ----
__global__ void hb_xconv(const float* __restrict__ x, short* __restrict__ xb) {
    const int i = blockIdx.x * blockDim.x + threadIdx.x;   // 65536 threads
    const fx4* xp = reinterpret_cast<const fx4*>(x) + (size_t)i * 2;
    fx4 a = xp[0], b = xp[1];
    bf16x8 o;
    #pragma unroll
    for (int j = 0; j < 4; ++j) { o[j] = bf16_rne(a[j]); o[j + 4] = bf16_rne(b[j]); }
    reinterpret_cast<bf16x8*>(xb)[i] = o;
}

// ---- main: binarize-on-the-fly MFMA GEMM + |w| sum; no LDS, no out atomics ----
// Each wave owns a 64(M) x 16(N) output tile over KBLK k; partials to ws.
__global__ __launch_bounds__(256, 6)
void hb_gemm(const float* __restrict__ w, const short* __restrict__ xb,
             float* __restrict__ part, float* __restrict__ absacc)
{
    const int tid  = threadIdx.x;
    const int wid  = tid >> 6;
    const int lane = tid & 63;
    const int lr   = lane & 15;                  // fragment row 0..15
    const int lg   = lane >> 4;                  // k-group 0..3

    const int kblk  = blockIdx.x & (KSPLIT - 1); // 16 k-blocks
    const int nbase = (blockIdx.x >> 4) * 64 + wid * 16;   // wave's 16 w-rows
    const int kbase = kblk * KBLK;

    const float* wp = w  + (size_t)(nbase + lr) * K_DIM + kbase + lg * 8;
    const short* xp = xb + (size_t)lr * K_DIM + kbase + lg * 8;

    fx4 acc[4] = {};
    float wabs = 0.f;

    #pragma unroll 2
    for (int ks = 0; ks < KBLK; ks += 32) {
        // B: 8 weight floats -> sign bf16, fused |w| accumulation
        const fx4 w0 = *reinterpret_cast<const fx4*>(wp + ks);
        const fx4 w1 = *reinterpret_cast<const fx4*>(wp + ks + 4);

        // A: 4 M-tiles of x (bf16, L2-resident)
        bf16x8 afrag[4];
        #pragma unroll
        for (int mt = 0; mt < 4; ++mt)
            afrag[mt] = *reinterpret_cast<const bf16x8*>(xp + (size_t)mt * 16 * K_DIM + ks);

        bf16x8 bfrag;
        #pragma unroll
        for (int j = 0; j < 4; ++j) {
            const float v0 = w0[j], v1 = w1[j];
            wabs += fabsf(v0);
            wabs += fabsf(v1);
            bfrag[j]     = (v0 > 0.f) ? (short)0x3F80 : ((v0 < 0.f) ? (short)0xBF80 : (short)0);
            bfrag[j + 4] = (v1 > 0.f) ? (short)0x3F80 : ((v1 < 0.f) ? (short)0xBF80 : (short)0);
        }

        #pragma unroll
        for (int mt = 0; mt < 4; ++mt)
            acc[mt] = __builtin_amdgcn_mfma_f32_16x16x32_bf16(afrag[mt], bfrag, acc[mt], 0, 0, 0);
    }

    // |w| partial: wave shuffle-reduce, one atomic per wave (8192 total)
    #pragma unroll
    for (int off = 32; off > 0; off >>= 1)
        wabs += __shfl_down(wabs, off);
    if (lane == 0) atomicAdd(absacc, wabs);

    // store unscaled partial tile: part[kblk][m][n], coalesced 64B segments
    float* pp = part + (size_t)kblk * (M_DIM * N_DIM) + nbase + lr;
    #pragma unroll
    for (int mt = 0; mt < 4; ++mt)
        #pragma unroll
        for (int j = 0; j < 4; ++j)
            pp[(size_t)(mt * 16 + lg * 4 + j) * N_DIM] = acc[mt][j];
}

// ---- finalize: out = scale * sum_k part[k] ----
__global__ void hb_reduce(const float* __restrict__ part,
                          const float* __restrict__ absacc,
                          float* __restrict__ out) {
    const float scale = absacc[0] * (1.0f / 67108864.0f);  // 1/(8192*8192)
    const int i = blockIdx.x * blockDim.x + threadIdx.x;    // 131072 threads, fx4 each
    fx4 s = reinterpret_cast<const fx4*>(part)[i];
    #pragma unroll
    for (int k = 1; k < KSPLIT; ++k)
        s += reinterpret_cast<const fx4*>(part)[(size_t)k * (M_DIM * N_DIM / 4) + i];
    s *= scale;
    reinterpret_cast<fx4*>(out)[i] = s;
}

extern "C" void kernel_launch(void* const* d_in, const int* in_sizes, int n_in,
                              void* d_out, int out_size, void* d_ws, size_t ws_size,
                              hipStream_t stream) {
    const float* x = (const float*)d_in[0];
    const float* w = (const float*)d_in[1];
    float* out = (float*)d_out;

    // ws layout: [0,64)=absacc | [4096, +1MB)=xb bf16 | [2MB, +32MB)=partials
    float* absacc = (float*)d_ws;
    short* xb     = (short*)((char*)d_ws + 4096);
    float* part   = (float*)((char*)d_ws + (2u << 20));

    hipMemsetAsync(d_ws, 0, 64, stream);
    hb_xconv<<<256, 256, 0, stream>>>(x, xb);
    hb_gemm<<<(N_DIM / 64) * KSPLIT, 256, 0, stream>>>(w, xb, part, absacc);
    hb_reduce<<<512, 256, 0, stream>>>(part, absacc, out);
}